// Round 7
// baseline (194.266 us; speedup 1.0000x reference)
//
#include <hip/hip_runtime.h>
#include <hip/hip_bf16.h>
#include <stdint.h>

// B=8, C=256, H=W=64 (N=4096), T=512
// out0 = F_s + (softmax(Fs_t @ Ft^T / sqrt(T)) @ Ft) in [B][C][N] layout, fp32
// out1 = P^T @ Fs_t   [B][T][C] fp32

typedef __attribute__((ext_vector_type(8))) short short8v;   // 8 bf16
typedef __attribute__((ext_vector_type(4))) float float4v;

#define MFMA16(a, b, c) __builtin_amdgcn_mfma_f32_16x16x32_bf16(a, b, c, 0, 0, 0)
#define SCALE 0.04419417382415922f  // 1/sqrt(512)

static __device__ __forceinline__ unsigned short f2bf(float f) {
  union { float f; uint32_t u; } v; v.f = f;
  uint32_t r = v.u + 0x7fffu + ((v.u >> 16) & 1u);   // RNE
  return (unsigned short)(r >> 16);
}

// ---------- cast + transpose (unchanged) ----------
__global__ __launch_bounds__(256) void k_cast_transpose(
    const float* __restrict__ src, unsigned short* __restrict__ dstC,
    unsigned short* __restrict__ dstT, int R, int Cd) {
  __shared__ unsigned short tile[32][33];
  const size_t zoff = (size_t)blockIdx.z * R * Cd;
  const float* s = src + zoff;
  unsigned short* dc = dstC + zoff;
  unsigned short* dt = dstT + zoff;
  const int c0 = blockIdx.x * 32, r0 = blockIdx.y * 32;
  const int tid = threadIdx.x;
  const int r = tid >> 3, c4 = (tid & 7) * 4;

  float4 v = *(const float4*)&s[(size_t)(r0 + r) * Cd + c0 + c4];
  ushort4 bq;
  bq.x = f2bf(v.x); bq.y = f2bf(v.y); bq.z = f2bf(v.z); bq.w = f2bf(v.w);
  *(ushort4*)&dc[(size_t)(r0 + r) * Cd + c0 + c4] = bq;
  tile[r][c4 + 0] = bq.x; tile[r][c4 + 1] = bq.y;
  tile[r][c4 + 2] = bq.z; tile[r][c4 + 3] = bq.w;
  __syncthreads();
  ushort4 o;
  o.x = tile[c4 + 0][r]; o.y = tile[c4 + 1][r];
  o.z = tile[c4 + 2][r]; o.w = tile[c4 + 3][r];
  *(ushort4*)&dt[(size_t)(c0 + r) * R + r0 + c4] = o;
}

// ---------- wave-autonomous fused attention ----------
// Each WAVE owns 16 q-rows x full T=512. No __syncthreads() anywhere:
//  - S (16x512) lives in acc[32] (128 VGPR/AGPR), softmax in-lane + shfl_xor.
//  - K / VT fragments read DIRECTLY from global (L2-resident, 256KB/batch each).
//  - P round-trips through a per-wave-PRIVATE LDS slice (q<->lane transpose),
//    so only same-wave lgkmcnt waits are needed.
// grid: 512 flat blocks (bid&7 = batch -> XCD-pinned K/VT), 256 threads (4 waves).
// LDS: 4 x [16][520] bf16 slices = 66,560 B -> 2 blocks/CU.
__global__ __launch_bounds__(256, 2) void k_attn(
    const unsigned short* __restrict__ Qg, const unsigned short* __restrict__ Kg,
    const unsigned short* __restrict__ VTg, const float* __restrict__ Fs,
    float* __restrict__ out0, unsigned short* __restrict__ PTg) {
  __shared__ unsigned short smem[4 * 16 * 520];

  const int tid = threadIdx.x;
  const int wave = tid >> 6, lane = tid & 63;
  const int l16 = lane & 15, lhi = lane >> 4;
  const int bid = blockIdx.x;
  const int b = bid & 7;            // batch == dispatch-round-robin XCD
  const int nb = bid >> 3;
  const int n0 = nb * 64 + wave * 16;   // this wave's 16 q-rows

  unsigned short* P = smem + wave * (16 * 520);   // private [16][520]

  const unsigned short* Qb = Qg + (size_t)b * 4096 * 256;
  const unsigned short* Kb = Kg + (size_t)b * 512 * 256;
  const unsigned short* VTb = VTg + (size_t)b * 256 * 512;

  // ---- Q fragments (A-operand rows = q = l16) ----
  short8v aQ[8];
#pragma unroll
  for (int kc = 0; kc < 8; kc++)
    aQ[kc] = *(const short8v*)(Qb + (size_t)(n0 + l16) * 256 + kc * 32 + lhi * 8);

  // ---- S = Q @ K^T : 32 t-tiles x 8 k-chunks, B-frags straight from L2 ----
  float4v acc[32];
#pragma unroll
  for (int tt = 0; tt < 32; tt++) acc[tt] = (float4v)0.f;

#pragma unroll
  for (int tg = 0; tg < 8; tg++) {
#pragma unroll
    for (int kc = 0; kc < 8; kc++) {
#pragma unroll
      for (int i = 0; i < 4; i++) {
        const int tt = tg * 4 + i;
        short8v bf = *(const short8v*)(Kb + (size_t)(tt * 16 + l16) * 256 + kc * 32 + lhi * 8);
        acc[tt] = MFMA16(aQ[kc], bf, acc[tt]);
      }
    }
  }

  // ---- exact softmax, fully in-wave ----
  // layout: per lane, tile tt holds t = tt*16 + l16 for q = lhi*4 + reg.
  float mx[4], sm[4];
#pragma unroll
  for (int r = 0; r < 4; r++) {
    float m = acc[0][r];
#pragma unroll
    for (int tt = 1; tt < 32; tt++) m = fmaxf(m, acc[tt][r]);
    m = fmaxf(m, __shfl_xor(m, 1));
    m = fmaxf(m, __shfl_xor(m, 2));
    m = fmaxf(m, __shfl_xor(m, 4));
    m = fmaxf(m, __shfl_xor(m, 8));
    mx[r] = m;
  }
#pragma unroll
  for (int r = 0; r < 4; r++) {
    float s = 0.f;
#pragma unroll
    for (int tt = 0; tt < 32; tt++) {
      float p = __expf((acc[tt][r] - mx[r]) * SCALE);  // scale folded into exp arg
      acc[tt][r] = p;
      s += p;
    }
    s += __shfl_xor(s, 1); s += __shfl_xor(s, 2);
    s += __shfl_xor(s, 4); s += __shfl_xor(s, 8);
    sm[r] = 1.0f / s;
  }

  // ---- P (bf16) -> private LDS slice [q][t], pitch 520 ----
#pragma unroll
  for (int tt = 0; tt < 32; tt++)
#pragma unroll
    for (int r = 0; r < 4; r++)
      P[(lhi * 4 + r) * 520 + tt * 16 + l16] = f2bf(acc[tt][r] * sm[r]);

  // ---- PT[b][t][n0..n0+15] from the slice (transposed reads, wave-local) ----
  {
    unsigned short* PTb = PTg + (size_t)b * 512 * 4096;
#pragma unroll
    for (int it = 0; it < 8; it++) {
      const int t = it * 64 + lane;
      unsigned short tmp[16];
#pragma unroll
      for (int q = 0; q < 16; q++) tmp[q] = P[q * 520 + t];
      *(int4*)(PTb + (size_t)t * 4096 + n0) = *(int4*)&tmp[0];
      *(int4*)(PTb + (size_t)t * 4096 + n0 + 8) = *(int4*)&tmp[8];
    }
  }

  // ---- O^T tiles: D[c][q] = VT(A) @ P(B);  B-frag = row l16 of P slice ----
  short8v pb[16];
#pragma unroll
  for (int kc = 0; kc < 16; kc++)
    pb[kc] = *(const short8v*)(P + l16 * 520 + kc * 32 + lhi * 8);

  float4v oacc[16];
#pragma unroll
  for (int ct = 0; ct < 16; ct++) oacc[ct] = (float4v)0.f;

#pragma unroll
  for (int cg = 0; cg < 4; cg++) {
#pragma unroll
    for (int kc = 0; kc < 16; kc++) {
#pragma unroll
      for (int i = 0; i < 4; i++) {
        const int ct = cg * 4 + i;
        short8v av = *(const short8v*)(VTb + (size_t)(ct * 16 + l16) * 512 + kc * 32 + lhi * 8);
        oacc[ct] = MFMA16(av, pb[kc], oacc[ct]);
      }
    }
  }

  // ---- epilogue: out0[b][c][n] = oacc + Fs, 64B-contiguous in n ----
  const float* Fsb = Fs + (size_t)b * 256 * 4096;
  float* o0 = out0 + (size_t)b * 256 * 4096;
#pragma unroll
  for (int ct = 0; ct < 16; ct++)
#pragma unroll
    for (int r = 0; r < 4; r++) {
      const int c = ct * 16 + lhi * 4 + r;
      const size_t off = (size_t)c * 4096 + n0 + l16;
      o0[off] = oacc[ct][r] + Fsb[off];
    }
}

// ---------- F_t_updated = PT @ Q  (B from QT), split-K=4, atomic (unchanged) ----------
__global__ __launch_bounds__(256) void k_ptq(
    const unsigned short* __restrict__ PTg, const unsigned short* __restrict__ QTg,
    float* __restrict__ out1) {
  __shared__ unsigned short As[64 * 72];
  __shared__ unsigned short Bs[64 * 72];
  const int tid = threadIdx.x;
  const int wave = tid >> 6, lane = tid & 63;
  const int l16 = lane & 15, lhi = lane >> 4;
  const int t0 = blockIdx.x * 64, c0 = blockIdx.y * 64;
  const int b = blockIdx.z >> 2, ksl = blockIdx.z & 3;
  const unsigned short* PTb = PTg + (size_t)b * 512 * 4096 + ksl * 1024;
  const unsigned short* QTb = QTg + (size_t)b * 256 * 4096 + ksl * 1024;
  const int wr = wave >> 1, wc = wave & 1;

  float4v acc[2][2];
#pragma unroll
  for (int mi = 0; mi < 2; mi++)
#pragma unroll
    for (int ni = 0; ni < 2; ni++) acc[mi][ni] = (float4v)0.f;

#pragma unroll 1
  for (int kk = 0; kk < 16; kk++) {
    __syncthreads();
#pragma unroll
    for (int i = 0; i < 2; i++) {
      int chunk = tid + i * 256;
      int row = chunk >> 3, col = (chunk & 7) * 8;
      *(int4*)(As + row * 72 + col) =
          *(const int4*)(PTb + (size_t)(t0 + row) * 4096 + kk * 64 + col);
      *(int4*)(Bs + row * 72 + col) =
          *(const int4*)(QTb + (size_t)(c0 + row) * 4096 + kk * 64 + col);
    }
    __syncthreads();
#pragma unroll
    for (int ks = 0; ks < 2; ks++) {
      short8v a0 = *(const short8v*)(As + (wr * 32 + l16) * 72 + ks * 32 + lhi * 8);
      short8v a1 = *(const short8v*)(As + (wr * 32 + 16 + l16) * 72 + ks * 32 + lhi * 8);
      short8v b0 = *(const short8v*)(Bs + (wc * 32 + l16) * 72 + ks * 32 + lhi * 8);
      short8v b1 = *(const short8v*)(Bs + (wc * 32 + 16 + l16) * 72 + ks * 32 + lhi * 8);
      acc[0][0] = MFMA16(a0, b0, acc[0][0]);
      acc[0][1] = MFMA16(a0, b1, acc[0][1]);
      acc[1][0] = MFMA16(a1, b0, acc[1][0]);
      acc[1][1] = MFMA16(a1, b1, acc[1][1]);
    }
  }
#pragma unroll
  for (int mi = 0; mi < 2; mi++)
#pragma unroll
    for (int ni = 0; ni < 2; ni++)
#pragma unroll
      for (int i = 0; i < 4; i++) {
        int t = t0 + wr * 32 + mi * 16 + lhi * 4 + i;
        int c = c0 + wc * 32 + ni * 16 + l16;
        atomicAdd(&out1[(size_t)(b * 512 + t) * 256 + c], acc[mi][ni][i]);
      }
}

extern "C" void kernel_launch(void* const* d_in, const int* in_sizes, int n_in,
                              void* d_out, int out_size, void* d_ws, size_t ws_size,
                              hipStream_t stream) {
  const float* Fs = (const float*)d_in[0];   // [8][256][4096]
  const float* Ft = (const float*)d_in[1];   // [8][512][256]
  float* out0 = (float*)d_out;               // [8][256][4096]
  float* out1 = out0 + (size_t)8 * 256 * 4096;  // [8][512][256]

  unsigned short* ws = (unsigned short*)d_ws;
  unsigned short* Q  = ws;               // [8][4096][256]
  unsigned short* QT = Q + 8388608;      // [8][256][4096]
  unsigned short* K  = QT + 8388608;     // [8][512][256]
  unsigned short* VT = K + 1048576;      // [8][256][512]
  unsigned short* PT = VT + 1048576;     // [8][512][4096]

  hipMemsetAsync(out1, 0, (size_t)1048576 * sizeof(float), stream);
  k_cast_transpose<<<dim3(128, 8, 8), 256, 0, stream>>>(Fs, QT, Q, 256, 4096);
  k_cast_transpose<<<dim3(8, 16, 8), 256, 0, stream>>>(Ft, K, VT, 512, 256);
  k_attn<<<dim3(512), 256, 0, stream>>>(Q, K, VT, Fs, out0, PT);
  k_ptq<<<dim3(8, 4, 32), 256, 0, stream>>>(PT, QT, out1);
}

// Round 8
// 117.261 us; speedup vs baseline: 1.6567x; 1.6567x over previous
//
#include <hip/hip_runtime.h>
#include <hip/hip_bf16.h>
#include <stdint.h>

// B=8, C=256, H=W=64 (N=4096), T=512
// out0 = F_s + (softmax(Fs_t @ Ft^T / sqrt(T)) @ Ft) in [B][C][N] layout, fp32
// out1 = P^T @ Fs_t   [B][T][C] fp32

typedef __attribute__((ext_vector_type(8))) short short8v;   // 8 bf16
typedef __attribute__((ext_vector_type(4))) float float4v;

#define MFMA16(a, b, c) __builtin_amdgcn_mfma_f32_16x16x32_bf16(a, b, c, 0, 0, 0)
#define SCALE 0.04419417382415922f  // 1/sqrt(512)

static __device__ __forceinline__ unsigned short f2bf(float f) {
  union { float f; uint32_t u; } v; v.f = f;
  uint32_t r = v.u + 0x7fffu + ((v.u >> 16) & 1u);   // RNE
  return (unsigned short)(r >> 16);
}

// async global->LDS, 16B per lane; LDS dest is wave-uniform base + lane*16
static __device__ __forceinline__ void gload16(const void* g, void* l) {
  __builtin_amdgcn_global_load_lds(
      (const __attribute__((address_space(1))) void*)g,
      (__attribute__((address_space(3))) void*)l, 16, 0, 0);
}

// ---------- cast + transpose (unchanged) ----------
__global__ __launch_bounds__(256) void k_cast_transpose(
    const float* __restrict__ src, unsigned short* __restrict__ dstC,
    unsigned short* __restrict__ dstT, int R, int Cd) {
  __shared__ unsigned short tile[32][33];
  const size_t zoff = (size_t)blockIdx.z * R * Cd;
  const float* s = src + zoff;
  unsigned short* dc = dstC + zoff;
  unsigned short* dt = dstT + zoff;
  const int c0 = blockIdx.x * 32, r0 = blockIdx.y * 32;
  const int tid = threadIdx.x;
  const int r = tid >> 3, c4 = (tid & 7) * 4;

  float4 v = *(const float4*)&s[(size_t)(r0 + r) * Cd + c0 + c4];
  ushort4 bq;
  bq.x = f2bf(v.x); bq.y = f2bf(v.y); bq.z = f2bf(v.z); bq.w = f2bf(v.w);
  *(ushort4*)&dc[(size_t)(r0 + r) * Cd + c0 + c4] = bq;
  tile[r][c4 + 0] = bq.x; tile[r][c4 + 1] = bq.y;
  tile[r][c4 + 2] = bq.z; tile[r][c4 + 3] = bq.w;
  __syncthreads();
  ushort4 o;
  o.x = tile[c4 + 0][r]; o.y = tile[c4 + 1][r];
  o.z = tile[c4 + 2][r]; o.w = tile[c4 + 3][r];
  *(ushort4*)&dt[(size_t)(c0 + r) * R + r0 + c4] = o;
}

// ---------- k_qks: S = Q@K^T, softmax, write P (row-major) + PT ----------
// grid 256 (32 n-tiles x 8 b), 512 threads (8 waves), QBLK=128 (16 q/wave).
// K staged per block: 8 chunks [64t][256k] = 32KB, double-buffered via
// global_load_lds (linear dest, pre-swizzled source; reads XOR-swizzled).
// LDS: K dbuf [0,65536) overlaid inside P slices 8 x [16][520] = 133,120 B.
__global__ __launch_bounds__(512, 2) void k_qks(
    const unsigned short* __restrict__ Qg, const unsigned short* __restrict__ Kg,
    unsigned short* __restrict__ Pg, unsigned short* __restrict__ PTg) {
  __shared__ char smem[133120];

  const int tid = threadIdx.x;
  const int wave = tid >> 6, lane = tid & 63;
  const int l16 = lane & 15, lhi = lane >> 4;
  const int b = blockIdx.x & 7, nb = blockIdx.x >> 3;
  const int n0w = nb * 128 + wave * 16;          // this wave's 16 q-rows
  const int cx = (l16 & 7) << 4;                 // read-side swizzle

  const unsigned short* Qb = Qg + (size_t)b * 4096 * 256;
  const char* Kb = (const char*)(Kg + (size_t)b * 512 * 256);

  // Q A-frags (rows = q = l16)
  short8v aQ[8];
#pragma unroll
  for (int kc = 0; kc < 8; kc++)
    aQ[kc] = *(const short8v*)(Qb + (size_t)(n0w + l16) * 256 + kc * 32 + lhi * 8);

  float4v acc[32];
#pragma unroll
  for (int tt = 0; tt < 32; tt++) acc[tt] = (float4v)0.f;

  // chunk c is a CONTIGUOUS 32KB slab of K (64 full rows); source pre-swizzled
  // with off ^ ((row&7)<<4) so LDS stays linear (rule #21).
#define STAGE_K(c_, buf_) do {                                              \
    const char* src_ = Kb + (c_) * 32768;                                   \
    _Pragma("unroll")                                                       \
    for (int i = 0; i < 4; i++) {                                           \
      const int off = (tid + i * 512) * 16;                                 \
      gload16(src_ + (off ^ (((off >> 9) & 7) << 4)),                       \
              smem + (buf_) * 32768 + off);                                 \
    } } while (0)

  STAGE_K(0, 0);
  __syncthreads();
#pragma unroll
  for (int c = 0; c < 8; c++) {
    const int buf = c & 1;
    if (c < 7) STAGE_K(c + 1, buf ^ 1);          // in flight across compute
#pragma unroll
    for (int ti = 0; ti < 4; ti++) {
      const int row = ti * 16 + l16;             // row&7 == l16&7
      const char* rb = smem + buf * 32768 + row * 512;
#pragma unroll
      for (int kc = 0; kc < 8; kc++) {
        short8v bf = *(const short8v*)(rb + ((kc * 64 + lhi * 16) ^ cx));
        acc[c * 4 + ti] = MFMA16(aQ[kc], bf, acc[c * 4 + ti]);
      }
    }
    __syncthreads();                             // drains stage c+1 (flew over MFMAs)
  }

  // ---- exact softmax, in-wave (r7-proven). lane: q = lhi*4+r, t = tt*16+l16 ----
  float mx[4], sm[4];
#pragma unroll
  for (int r = 0; r < 4; r++) {
    float m = acc[0][r];
#pragma unroll
    for (int tt = 1; tt < 32; tt++) m = fmaxf(m, acc[tt][r]);
    m = fmaxf(m, __shfl_xor(m, 1));
    m = fmaxf(m, __shfl_xor(m, 2));
    m = fmaxf(m, __shfl_xor(m, 4));
    m = fmaxf(m, __shfl_xor(m, 8));
    mx[r] = m;
  }
#pragma unroll
  for (int r = 0; r < 4; r++) {
    float s = 0.f;
#pragma unroll
    for (int tt = 0; tt < 32; tt++) {
      float p = __expf((acc[tt][r] - mx[r]) * SCALE);
      acc[tt][r] = p;
      s += p;
    }
    s += __shfl_xor(s, 1); s += __shfl_xor(s, 2);
    s += __shfl_xor(s, 4); s += __shfl_xor(s, 8);
    sm[r] = 1.0f / s;
  }

  // ---- P -> per-wave LDS slice [16][520] (overlays dead K bufs; fenced by last barrier) ----
  unsigned short* Ps = (unsigned short*)smem + wave * 8320;
#pragma unroll
  for (int tt = 0; tt < 32; tt++)
#pragma unroll
    for (int r = 0; r < 4; r++)
      Ps[(lhi * 4 + r) * 520 + tt * 16 + l16] = f2bf(acc[tt][r] * sm[r]);

  // ---- P row-major to global (coalesced via slice) ----
  {
    unsigned short* Pgb = Pg + ((size_t)b * 4096 + n0w) * 512;
#pragma unroll
    for (int j = 0; j < 16; j++) {
      short8v v = *(const short8v*)(Ps + j * 520 + lane * 8);
      *(short8v*)(Pgb + (size_t)j * 512 + lane * 8) = v;
    }
  }

  // ---- PT[b][t][n0w..+15] (r7-proven transpose reads) ----
  {
    unsigned short* PTb = PTg + (size_t)b * 512 * 4096;
#pragma unroll
    for (int it = 0; it < 8; it++) {
      const int t = it * 64 + lane;
      unsigned short tmp[16];
#pragma unroll
      for (int q = 0; q < 16; q++) tmp[q] = Ps[q * 520 + t];
      *(int4*)(PTb + (size_t)t * 4096 + n0w) = *(int4*)&tmp[0];
      *(int4*)(PTb + (size_t)t * 4096 + n0w + 8) = *(int4*)&tmp[8];
    }
  }
#undef STAGE_K
}

// ---------- k_pv: out0 = P @ V + Fs (transposed layout) ----------
// grid 256, 512 threads (8 waves), QBLK=128 (16 q/wave), C=256.
// VT staged per block: 8 chunks [256c][64t] = 32KB, dbuf via global_load_lds.
// P B-frags read direct from global (each row read once per wave). LDS 64KB.
__global__ __launch_bounds__(512, 2) void k_pv(
    const unsigned short* __restrict__ Pg, const unsigned short* __restrict__ VTg,
    const float* __restrict__ Fs, float* __restrict__ out0) {
  __shared__ char smem[65536];

  const int tid = threadIdx.x;
  const int wave = tid >> 6, lane = tid & 63;
  const int l16 = lane & 15, lhi = lane >> 4;
  const int b = blockIdx.x & 7, nb = blockIdx.x >> 3;
  const int n0w = nb * 128 + wave * 16;
  const int cx = (l16 & 7) << 4;

  const char* VTb = (const char*)(VTg + (size_t)b * 256 * 512);
  const unsigned short* Prow = Pg + ((size_t)b * 4096 + n0w + l16) * 512 + lhi * 8;

#define STAGE_V(c_, buf_) do {                                              \
    _Pragma("unroll")                                                       \
    for (int i = 0; i < 4; i++) {                                           \
      const int off = (tid + i * 512) * 16;                                 \
      const int r_ = off >> 7, ic_ = off & 127;                             \
      gload16(VTb + (size_t)r_ * 1024 + (c_) * 128 + (ic_ ^ ((r_ & 7) << 4)), \
              smem + (buf_) * 32768 + off);                                 \
    } } while (0)

  float4v oacc[16];
#pragma unroll
  for (int ct = 0; ct < 16; ct++) oacc[ct] = (float4v)0.f;

  STAGE_V(0, 0);
  __syncthreads();
#pragma unroll
  for (int c = 0; c < 8; c++) {
    const int buf = c & 1;
    // B-frags (own P rows) FIRST so their wait doesn't drain the stage queue
    short8v pb0 = *(const short8v*)(Prow + c * 64);
    short8v pb1 = *(const short8v*)(Prow + c * 64 + 32);
    if (c < 7) STAGE_V(c + 1, buf ^ 1);
#pragma unroll
    for (int ct = 0; ct < 16; ct++) {
      const int row = ct * 16 + l16;             // row&7 == l16&7
      const char* rb = smem + buf * 32768 + row * 128;
      short8v a0 = *(const short8v*)(rb + ((lhi * 16) ^ cx));
      oacc[ct] = MFMA16(a0, pb0, oacc[ct]);
      short8v a1 = *(const short8v*)(rb + ((64 + lhi * 16) ^ cx));
      oacc[ct] = MFMA16(a1, pb1, oacc[ct]);
    }
    __syncthreads();
  }

  // ---- epilogue: out0[b][c][n] = oacc + Fs (r7-proven direct stores) ----
  const float* Fsb = Fs + (size_t)b * 256 * 4096;
  float* o0 = out0 + (size_t)b * 256 * 4096;
#pragma unroll
  for (int ct = 0; ct < 16; ct++)
#pragma unroll
    for (int r = 0; r < 4; r++) {
      const int cgl = ct * 16 + lhi * 4 + r;
      const size_t off = (size_t)cgl * 4096 + n0w + l16;
      o0[off] = oacc[ct][r] + Fsb[off];
    }
#undef STAGE_V
}

// ---------- F_t_updated = PT @ Q (B from QT), split-K=4, atomic (unchanged) ----------
__global__ __launch_bounds__(256) void k_ptq(
    const unsigned short* __restrict__ PTg, const unsigned short* __restrict__ QTg,
    float* __restrict__ out1) {
  __shared__ unsigned short As[64 * 72];
  __shared__ unsigned short Bs[64 * 72];
  const int tid = threadIdx.x;
  const int wave = tid >> 6, lane = tid & 63;
  const int l16 = lane & 15, lhi = lane >> 4;
  const int t0 = blockIdx.x * 64, c0 = blockIdx.y * 64;
  const int b = blockIdx.z >> 2, ksl = blockIdx.z & 3;
  const unsigned short* PTb = PTg + (size_t)b * 512 * 4096 + ksl * 1024;
  const unsigned short* QTb = QTg + (size_t)b * 256 * 4096 + ksl * 1024;
  const int wr = wave >> 1, wc = wave & 1;

  float4v acc[2][2];
#pragma unroll
  for (int mi = 0; mi < 2; mi++)
#pragma unroll
    for (int ni = 0; ni < 2; ni++) acc[mi][ni] = (float4v)0.f;

#pragma unroll 1
  for (int kk = 0; kk < 16; kk++) {
    __syncthreads();
#pragma unroll
    for (int i = 0; i < 2; i++) {
      int chunk = tid + i * 256;
      int row = chunk >> 3, col = (chunk & 7) * 8;
      *(int4*)(As + row * 72 + col) =
          *(const int4*)(PTb + (size_t)(t0 + row) * 4096 + kk * 64 + col);
      *(int4*)(Bs + row * 72 + col) =
          *(const int4*)(QTb + (size_t)(c0 + row) * 4096 + kk * 64 + col);
    }
    __syncthreads();
#pragma unroll
    for (int ks = 0; ks < 2; ks++) {
      short8v a0 = *(const short8v*)(As + (wr * 32 + l16) * 72 + ks * 32 + lhi * 8);
      short8v a1 = *(const short8v*)(As + (wr * 32 + 16 + l16) * 72 + ks * 32 + lhi * 8);
      short8v b0 = *(const short8v*)(Bs + (wc * 32 + l16) * 72 + ks * 32 + lhi * 8);
      short8v b1 = *(const short8v*)(Bs + (wc * 32 + 16 + l16) * 72 + ks * 32 + lhi * 8);
      acc[0][0] = MFMA16(a0, b0, acc[0][0]);
      acc[0][1] = MFMA16(a0, b1, acc[0][1]);
      acc[1][0] = MFMA16(a1, b0, acc[1][0]);
      acc[1][1] = MFMA16(a1, b1, acc[1][1]);
    }
  }
#pragma unroll
  for (int mi = 0; mi < 2; mi++)
#pragma unroll
    for (int ni = 0; ni < 2; ni++)
#pragma unroll
      for (int i = 0; i < 4; i++) {
        int t = t0 + wr * 32 + mi * 16 + lhi * 4 + i;
        int c = c0 + wc * 32 + ni * 16 + l16;
        atomicAdd(&out1[(size_t)(b * 512 + t) * 256 + c], acc[mi][ni][i]);
      }
}

extern "C" void kernel_launch(void* const* d_in, const int* in_sizes, int n_in,
                              void* d_out, int out_size, void* d_ws, size_t ws_size,
                              hipStream_t stream) {
  const float* Fs = (const float*)d_in[0];   // [8][256][4096]
  const float* Ft = (const float*)d_in[1];   // [8][512][256]
  float* out0 = (float*)d_out;               // [8][256][4096]
  float* out1 = out0 + (size_t)8 * 256 * 4096;  // [8][512][256]

  unsigned short* ws = (unsigned short*)d_ws;
  unsigned short* Q  = ws;                // [8][4096][256]
  unsigned short* QT = Q + 8388608;       // [8][256][4096]
  unsigned short* K  = QT + 8388608;      // [8][512][256]
  unsigned short* VT = K + 1048576;       // [8][256][512]
  unsigned short* PT = VT + 1048576;      // [8][512][4096]
  unsigned short* P  = PT + 16777216;     // [8][4096][512]
  // ws use: 104,857,600 bytes

  hipMemsetAsync(out1, 0, (size_t)1048576 * sizeof(float), stream);
  k_cast_transpose<<<dim3(128, 8, 8), 256, 0, stream>>>(Fs, QT, Q, 256, 4096);
  k_cast_transpose<<<dim3(8, 16, 8), 256, 0, stream>>>(Ft, K, VT, 512, 256);
  k_qks<<<dim3(256), 512, 0, stream>>>(Q, K, P, PT);
  k_pv<<<dim3(256), 512, 0, stream>>>(P, VT, Fs, out0);
  k_ptq<<<dim3(8, 4, 32), 256, 0, stream>>>(PT, QT, out1);
}